// Round 5
// baseline (236442.407 us; speedup 1.0000x reference)
//
#include <hip/hip_runtime.h>
#include <math.h>

// Invariant-EKF sequential scan, single persistent workgroup (1 CU).
// 7 waves x 64 lanes. Thread (i,j) of the 21x21 covariance grid keeps P[i][j]
// in a register; LDS holds transient 21x21 buffers (stride 22 -> only 2-way
// bank aliasing, free on CDNA4). Phi is applied analytically (block-sparse,
// F^4 = 0), the Joseph update as a rank-2 correction computed in BOTH
// orientations per-thread so symmetrization needs no extra barrier.
// 5 __syncthreads() per step. Global inputs (t/u/mc) software-pipelined one
// iteration ahead so load latency overlaps compute.

#define GRAV 9.80665f
#define LDP 22   // 21x21 matrix row pitch (floats)
#define SP  24   // small-row pitch (floats), 16B aligned for ds_read_b128
#define Q0c 0.001f
#define Q1c 0.01f

__device__ __forceinline__ float sel3f(int r, float a, float b, float c) {
    return (r == 0) ? a : ((r == 1) ? b : c);
}

__device__ __forceinline__ void m3mul_dev(const float* A, const float* B, float* C) {
#pragma unroll
    for (int i = 0; i < 3; ++i) {
#pragma unroll
        for (int j = 0; j < 3; ++j) {
            C[i*3+j] = A[i*3+0]*B[j] + A[i*3+1]*B[3+j] + A[i*3+2]*B[6+j];
        }
    }
}

__device__ __forceinline__ void so3exp_dev(float p0, float p1, float p2, float* R) {
    float sq = p0*p0 + p1*p1 + p2*p2;
    if (sq < 1e-16f) {
        R[0]=1.f;  R[1]=-p2;  R[2]=p1;
        R[3]=p2;   R[4]=1.f;  R[5]=-p0;
        R[6]=-p1;  R[7]=p0;   R[8]=1.f;
    } else {
        float ang = sqrtf(sq);
        float ax=p0/ang, ay=p1/ang, az=p2/ang;
        float s=sinf(ang), c=cosf(ang), o=1.f-c;
        R[0]=c+o*ax*ax;    R[1]=o*ax*ay-s*az; R[2]=o*ax*az+s*ay;
        R[3]=o*ay*ax+s*az; R[4]=c+o*ay*ay;    R[5]=o*ay*az-s*ax;
        R[6]=o*az*ax-s*ay; R[7]=o*az*ay+s*ax; R[8]=c+o*az*az;
    }
}

// wave 6, lanes 0..32 write the 33 trajectory scalars for row NIDX
#define STORE_TRAJ(NIDX)                                                        \
    do {                                                                        \
        if (w == 6 && l < 33) {                                                 \
            float val = Rot[0];                                                 \
            if (l==1) val=Rot[1];  if (l==2) val=Rot[2];                        \
            if (l==3) val=Rot[3];  if (l==4) val=Rot[4];                        \
            if (l==5) val=Rot[5];  if (l==6) val=Rot[6];                        \
            if (l==7) val=Rot[7];  if (l==8) val=Rot[8];                        \
            if (l==9)  val=vv[0];  if (l==10) val=vv[1];  if (l==11) val=vv[2]; \
            if (l==12) val=pp[0];  if (l==13) val=pp[1];  if (l==14) val=pp[2]; \
            if (l==15) val=bw[0];  if (l==16) val=bw[1];  if (l==17) val=bw[2]; \
            if (l==18) val=ba[0];  if (l==19) val=ba[1];  if (l==20) val=ba[2]; \
            if (l==21) val=Rci[0]; if (l==22) val=Rci[1]; if (l==23) val=Rci[2];\
            if (l==24) val=Rci[3]; if (l==25) val=Rci[4]; if (l==26) val=Rci[5];\
            if (l==27) val=Rci[6]; if (l==28) val=Rci[7]; if (l==29) val=Rci[8];\
            if (l==30) val=tci[0]; if (l==31) val=tci[1]; if (l==32) val=tci[2];\
            out[ob + os_ * (NIDX) + orr] = val;                                 \
        }                                                                       \
    } while (0)

__global__ __launch_bounds__(448)
void iekf_scan_kernel(const float* __restrict__ t,
                      const float* __restrict__ u,
                      const float* __restrict__ mc,
                      const float* __restrict__ v_mes,
                      const float* __restrict__ ang0,
                      float* __restrict__ out,
                      const int N)
{
    __shared__ __align__(16) float sA [21*LDP];
    __shared__ __align__(16) float sT1[21*LDP];
    __shared__ __align__(16) float sPn[21*LDP];
    __shared__ __align__(16) float sH  [2*SP];
    __shared__ __align__(16) float sHP [2*SP];
    __shared__ __align__(16) float sHPT[2*SP];
    __shared__ __align__(16) float sK0 [SP];
    __shared__ __align__(16) float sK1 [SP];
    __shared__ __align__(16) float sKS0[SP];
    __shared__ __align__(16) float sKS1[SP];
    __shared__ __align__(16) float sdx [SP];
    __shared__ float sr[2];

    const int tid = (int)threadIdx.x;
    const int w   = tid >> 6;        // wave id 0..6 (= block-row of 21x21 grid)
    const int l   = tid & 63;
    const int li  = l / 21;          // 0..2 local row (lane 63 -> 3, always masked)
    const int lj  = l % 21;          // column
    const bool act = (l < 63);
    const int i_row = 3*w + li;      // mapping A: global row
    const bool repl = (w <= 2) || (w == 6);  // waves that carry the small state

    // ---- initial small state (replicated registers) ----
    float Rot[9], vv[3], pp[3], bw[3], ba[3], Rci[9], tci[3];
    {
        const float roll = ang0[0], pitch = ang0[1], yaw = ang0[2];
        const float cr = cosf(roll),  srl = sinf(roll);
        const float cp = cosf(pitch), spt = sinf(pitch);
        const float cy = cosf(yaw),   syw = sinf(yaw);
        float rx[9] = {1.f,0.f,0.f, 0.f,cr,-srl, 0.f,srl,cr};
        float ry[9] = {cp,0.f,spt, 0.f,1.f,0.f, -spt,0.f,cp};
        float rz[9] = {cy,-syw,0.f, syw,cy,0.f, 0.f,0.f,1.f};
        float tm[9]; m3mul_dev(rz, ry, tm);
        m3mul_dev(tm, rx, Rot);
        vv[0]=v_mes[0]; vv[1]=v_mes[1]; vv[2]=v_mes[2];
#pragma unroll
        for (int c=0;c<3;c++){ pp[c]=0.f; bw[c]=0.f; ba[c]=0.f; tci[c]=0.f; }
        Rci[0]=1.f;Rci[1]=0.f;Rci[2]=0.f;Rci[3]=0.f;Rci[4]=1.f;Rci[5]=0.f;
        Rci[6]=0.f;Rci[7]=0.f;Rci[8]=1.f;
    }

    // ---- own covariance element P[i_row][lj] ----
    float Preg = 0.f;
    if (act && i_row == lj) {
        const int ii = i_row;
        float pd = 0.f;
        if (ii==0 || ii==1)        pd = 0.001f;   // COV_ROT0 (z entry = 0)
        else if (ii==3 || ii==4)   pd = 0.1f;     // COV_V0
        else if (ii>=9  && ii<12)  pd = 0.006f;   // b_omega
        else if (ii>=12 && ii<15)  pd = 0.004f;   // b_acc
        else if (ii>=15 && ii<18)  pd = 1e-6f;    // Rot_c_i
        else if (ii>=18)           pd = 0.005f;   // t_c_i
        Preg = pd;
    }

    // ---- per-lane output address constants (wave 6) ----
    int ob=0, os_=0, orr=0;
    if (w==6 && l<33) {
        if (l<9)       { ob = 0;    os_ = 9; orr = l;    }
        else if (l<12) { ob = 9*N;  os_ = 3; orr = l-9;  }
        else if (l<15) { ob = 12*N; os_ = 3; orr = l-12; }
        else if (l<18) { ob = 15*N; os_ = 3; orr = l-15; }
        else if (l<21) { ob = 18*N; os_ = 3; orr = l-18; }
        else if (l<30) { ob = 21*N; os_ = 9; orr = l-21; }
        else           { ob = 30*N; os_ = 3; orr = l-30; }
    }

    STORE_TRAJ(0);

    float t_cur = t[0];

    // ---- software-pipelined input registers (current iteration's inputs) ----
    float tn_c = t[1];
    float uc0=0.f,uc1=0.f,uc2=0.f,uc3=0.f,uc4=0.f,uc5=0.f;
    if (repl) {
        const float* un = u + 6;             // index n+1 = 1
        uc0=un[0]; uc1=un[1]; uc2=un[2]; uc3=un[3]; uc4=un[4]; uc5=un[5];
    }
    float mcc0=0.f, mcc1=0.f;
    if (w == 5) { mcc0 = mc[2]; mcc1 = mc[3]; }

    for (int n = 0; n < N-1; ++n) {
        // ---- prefetch next iteration's inputs (index n+2, clamped) ----
        const int np2 = (n+2 < N) ? (n+2) : (N-1);
        const float tn_n = t[np2];
        float un0=0.f,un1=0.f,un2=0.f,un3=0.f,un4=0.f,un5=0.f;
        if (repl) {
            const float* un = u + (size_t)np2*6;
            un0=un[0]; un1=un[1]; un2=un[2]; un3=un[3]; un4=un[4]; un5=un[5];
        }
        float mcn0=0.f, mcn1=0.f;
        if (w == 5) { mcn0 = mc[2*np2]; mcn1 = mc[2*np2+1]; }

        const float dt  = tn_c - t_cur;
        const float dt2 = dt*dt;
        const float u0=uc0,u1=uc1,u2=uc2,u3=uc3,u4=uc4,u5=uc5;
        const float mcv0=mcc0, mcv1=mcc1;

        // ============== phase 0: small state + A = P + G Q G^T ==============
        float Rot_n[9], v_n[3], p_n[3], om[3];
        float M1[9], M2[9], cbw[3], cba[3];
        float dtg=0.f, hg=0.f;

        if (repl) {
            om[0]=u0-bw[0]; om[1]=u1-bw[1]; om[2]=u2-bw[2];
            const float ai0=u3-ba[0], ai1=u4-ba[1], ai2=u5-ba[2];
            const float ac0 = Rot[0]*ai0 + Rot[1]*ai1 + Rot[2]*ai2;
            const float ac1 = Rot[3]*ai0 + Rot[4]*ai1 + Rot[5]*ai2;
            const float ac2 = Rot[6]*ai0 + Rot[7]*ai1 + Rot[8]*ai2 - GRAV;
            v_n[0]=vv[0]+ac0*dt; v_n[1]=vv[1]+ac1*dt; v_n[2]=vv[2]+ac2*dt;
            p_n[0]=pp[0]+vv[0]*dt+0.5f*ac0*dt2;
            p_n[1]=pp[1]+vv[1]*dt+0.5f*ac1*dt2;
            p_n[2]=pp[2]+vv[2]*dt+0.5f*ac2*dt2;
            float E[9]; so3exp_dev(om[0]*dt, om[1]*dt, om[2]*dt, E);
            m3mul_dev(Rot, E, Rot_n);
        }

        if (w <= 2) {
            // M1 = skew(v)@Rot, M2 = skew(p)@Rot  (old state, as in reference)
#pragma unroll
            for (int c=0;c<3;c++) {
                M1[0+c] = -vv[2]*Rot[3+c] + vv[1]*Rot[6+c];
                M1[3+c] =  vv[2]*Rot[0+c] - vv[0]*Rot[6+c];
                M1[6+c] = -vv[1]*Rot[0+c] + vv[0]*Rot[3+c];
                M2[0+c] = -pp[2]*Rot[3+c] + pp[1]*Rot[6+c];
                M2[3+c] =  pp[2]*Rot[0+c] - pp[0]*Rot[6+c];
                M2[6+c] = -pp[1]*Rot[0+c] + pp[0]*Rot[3+c];
            }
            const float hdt2 = 0.5f*dt2;
            const float sdt3 = dt*dt2*(1.0f/6.0f);
            dtg = dt*GRAV; hg = hdt2*GRAV;
            // Phi coefficients for (own block-row, b_omega cols) and (.., b_acc cols)
#pragma unroll
            for (int c=0;c<3;c++) {
                const float m0r = sel3f(li, Rot[0+c], Rot[3+c], Rot[6+c]);
                const float m1r = sel3f(li, M1[0+c], M1[3+c], M1[6+c]);
                const float m2r = sel3f(li, M2[0+c], M2[3+c], M2[6+c]);
                const float sgm = sel3f(li, GRAV*Rot[3+c], -GRAV*Rot[0+c], 0.f); // (Sg*Rot)[li][c]
                if (w == 0)      { cbw[c] = -dt*m0r;                       cba[c] = 0.f; }
                else if (w == 1) { cbw[c] = -dt*m1r - hdt2*sgm;            cba[c] = -dt*m0r; }
                else             { cbw[c] = -dt*m2r - hdt2*m1r - sdt3*sgm; cba[c] = -hdt2*m0r; }
            }
        }

        if (w == 6) {
            // measurement row H (2x21) + residual r
            float Rb[9]; m3mul_dev(Rot_n, Rci, Rb);               // Rot_body
            const float vi0 = Rot_n[0]*v_n[0] + Rot_n[3]*v_n[1] + Rot_n[6]*v_n[2];
            const float vi1 = Rot_n[1]*v_n[0] + Rot_n[4]*v_n[1] + Rot_n[7]*v_n[2];
            const float vi2 = Rot_n[2]*v_n[0] + Rot_n[5]*v_n[1] + Rot_n[8]*v_n[2];
            float Hv1[3], Hv2[3];                                 // rows 1,2 of Rci^T@skew(v_imu)
            Hv1[0] =  Rci[4]*vi2 - Rci[7]*vi1;
            Hv1[1] = -Rci[1]*vi2 + Rci[7]*vi0;
            Hv1[2] =  Rci[1]*vi1 - Rci[4]*vi0;
            Hv2[0] =  Rci[5]*vi2 - Rci[8]*vi1;
            Hv2[1] = -Rci[2]*vi2 + Rci[8]*vi0;
            Hv2[2] =  Rci[2]*vi1 - Rci[5]*vi0;
            const float vb1 = Rci[1]*vi0 + Rci[4]*vi1 + Rci[7]*vi2 + (tci[2]*om[0] - tci[0]*om[2]);
            const float vb2 = Rci[2]*vi0 + Rci[5]*vi1 + Rci[8]*vi2 + (tci[0]*om[1] - tci[1]*om[0]);
            if (l < 42) {
                const int a  = l / 21;
                const int jj = l - 21*a;
                const int bj = jj / 3;
                const int rj = jj - 3*bj;
                float val = 0.f;
                if (bj == 1) {            // cols 3:6  = Rot_body.T[1+a]
                    val = (a==0) ? sel3f(rj, Rb[1], Rb[4], Rb[7])
                                 : sel3f(rj, Rb[2], Rb[5], Rb[8]);
                } else if (bj == 3) {     // cols 9:12 = skew(t_c_i)[1+a]
                    val = (a==0) ? sel3f(rj, tci[2], 0.f, -tci[0])
                                 : sel3f(rj, -tci[1], tci[0], 0.f);
                } else if (bj == 5) {     // cols 15:18
                    val = (a==0) ? sel3f(rj, Hv1[0], Hv1[1], Hv1[2])
                                 : sel3f(rj, Hv2[0], Hv2[1], Hv2[2]);
                } else if (bj == 6) {     // cols 18:21 = -skew(omega)[1+a]
                    val = (a==0) ? sel3f(rj, -om[2], 0.f, om[0])
                                 : sel3f(rj, om[1], -om[0], 0.f);
                }
                sH[a*SP + jj] = val;
            }
            if (l == 0) { sr[0] = -vb1; sr[1] = -vb2; }
        }

        // A = P + G Q G^T (analytic, each thread its own element)
        float Aij = 0.f;
        if (act) {
            float Wij = 0.f;
            const int bj = lj / 3;
            const int rj = lj - 3*bj;
            if (w <= 2) {
                if (bj <= 2) {
                    float ma0, ma1, ma2;
                    if (w == 0)      { ma0=sel3f(li,Rot[0],Rot[3],Rot[6]); ma1=sel3f(li,Rot[1],Rot[4],Rot[7]); ma2=sel3f(li,Rot[2],Rot[5],Rot[8]); }
                    else if (w == 1) { ma0=sel3f(li,M1[0],M1[3],M1[6]);    ma1=sel3f(li,M1[1],M1[4],M1[7]);    ma2=sel3f(li,M1[2],M1[5],M1[8]); }
                    else             { ma0=sel3f(li,M2[0],M2[3],M2[6]);    ma1=sel3f(li,M2[1],M2[4],M2[7]);    ma2=sel3f(li,M2[2],M2[5],M2[8]); }
                    float mb0, mb1, mb2;
                    if (bj == 0)      { mb0=sel3f(rj,Rot[0],Rot[3],Rot[6]); mb1=sel3f(rj,Rot[1],Rot[4],Rot[7]); mb2=sel3f(rj,Rot[2],Rot[5],Rot[8]); }
                    else if (bj == 1) { mb0=sel3f(rj,M1[0],M1[3],M1[6]);    mb1=sel3f(rj,M1[1],M1[4],M1[7]);    mb2=sel3f(rj,M1[2],M1[5],M1[8]); }
                    else              { mb0=sel3f(rj,M2[0],M2[3],M2[6]);    mb1=sel3f(rj,M2[1],M2[4],M2[7]);    mb2=sel3f(rj,M2[2],M2[5],M2[8]); }
                    Wij = dt2*Q0c*(ma0*mb0 + ma1*mb1 + ma2*mb2);
                    if (w == 1 && bj == 1) {
                        const float ra0=sel3f(li,Rot[0],Rot[3],Rot[6]), ra1=sel3f(li,Rot[1],Rot[4],Rot[7]), ra2=sel3f(li,Rot[2],Rot[5],Rot[8]);
                        const float rb0=sel3f(rj,Rot[0],Rot[3],Rot[6]), rb1=sel3f(rj,Rot[1],Rot[4],Rot[7]), rb2=sel3f(rj,Rot[2],Rot[5],Rot[8]);
                        Wij += dt2*Q1c*(ra0*rb0 + ra1*rb1 + ra2*rb2);
                    }
                }
            } else {
                const float qd = (w==3) ? 6e-9f : (w==4) ? 2e-4f : (w==5) ? 1e-9f : 1e-9f;
                if (i_row == lj) Wij = dt2*qd;
            }
            Aij = Preg + Wij;
            sA[i_row*LDP + lj] = Aij;
        }

        // ============== phase 1: T1 = Phi @ A (row-block sparse) ==============
        __syncthreads();
        float T1ij = Aij;
        if (act) {
            if (w == 0) {
                T1ij += cbw[0]*sA[ 9*LDP+lj];
                T1ij += cbw[1]*sA[10*LDP+lj];
                T1ij += cbw[2]*sA[11*LDP+lj];
            } else if (w == 1) {
                const float a0 = sA[0*LDP+lj], a1 = sA[1*LDP+lj];
                T1ij += dtg * sel3f(li, a1, -a0, 0.f);
                T1ij += cbw[0]*sA[ 9*LDP+lj];
                T1ij += cbw[1]*sA[10*LDP+lj];
                T1ij += cbw[2]*sA[11*LDP+lj];
                T1ij += cba[0]*sA[12*LDP+lj];
                T1ij += cba[1]*sA[13*LDP+lj];
                T1ij += cba[2]*sA[14*LDP+lj];
            } else if (w == 2) {
                const float a0 = sA[0*LDP+lj], a1 = sA[1*LDP+lj];
                T1ij += hg * sel3f(li, a1, -a0, 0.f);
                T1ij += dt * sA[(3+li)*LDP+lj];
                T1ij += cbw[0]*sA[ 9*LDP+lj];
                T1ij += cbw[1]*sA[10*LDP+lj];
                T1ij += cbw[2]*sA[11*LDP+lj];
                T1ij += cba[0]*sA[12*LDP+lj];
                T1ij += cba[1]*sA[13*LDP+lj];
                T1ij += cba[2]*sA[14*LDP+lj];
            }
            sT1[i_row*LDP + lj] = T1ij;
        }

        // ============== phase 2: Pn = T1 @ Phi^T (column-block mapping) =======
        __syncthreads();
        if (act) {
            const int iB = lj;            // row
            const int jB = 3*w + li;      // column (wave owns a block-column)
            const int rb = iB*LDP;
            float pn = sT1[rb + jB];
            if (w == 0) {
                pn += cbw[0]*sT1[rb+ 9];
                pn += cbw[1]*sT1[rb+10];
                pn += cbw[2]*sT1[rb+11];
            } else if (w == 1) {
                const float b0 = sT1[rb+0], b1 = sT1[rb+1];
                pn += dtg * sel3f(li, b1, -b0, 0.f);
                pn += cbw[0]*sT1[rb+ 9];
                pn += cbw[1]*sT1[rb+10];
                pn += cbw[2]*sT1[rb+11];
                pn += cba[0]*sT1[rb+12];
                pn += cba[1]*sT1[rb+13];
                pn += cba[2]*sT1[rb+14];
            } else if (w == 2) {
                const float b0 = sT1[rb+0], b1 = sT1[rb+1];
                pn += hg * sel3f(li, b1, -b0, 0.f);
                pn += dt * sT1[rb+3+li];
                pn += cbw[0]*sT1[rb+ 9];
                pn += cbw[1]*sT1[rb+10];
                pn += cbw[2]*sT1[rb+11];
                pn += cba[0]*sT1[rb+12];
                pn += cba[1]*sT1[rb+13];
                pn += cba[2]*sT1[rb+14];
            }
            sPn[rb + jB] = pn;
        }

        // ============== phase 3: HP = H@Pn, HPT = H@Pn^T ======================
        __syncthreads();
        if (w == 3 && l < 42) {
            const int a = l/21, jj = l - 21*a;
            float acc = 0.f;
            const int hix[12] = {3,4,5,9,10,11,15,16,17,18,19,20};
#pragma unroll
            for (int q=0;q<12;q++) acc += sH[a*SP + hix[q]] * sPn[hix[q]*LDP + jj];
            sHP[a*SP + jj] = acc;
        }
        if (w == 4 && l < 42) {
            const int a = l/21, jj = l - 21*a;
            float acc = 0.f;
            const int hix[12] = {3,4,5,9,10,11,15,16,17,18,19,20};
#pragma unroll
            for (int q=0;q<12;q++) acc += sH[a*SP + hix[q]] * sPn[jj*LDP + hix[q]];
            sHPT[a*SP + jj] = acc;
        }

        // ============== phase 4: S, 2x2 pivoted solve, K, dx ==================
        __syncthreads();
        if (w == 5) {
            float S00=0.f,S01=0.f,S10=0.f,S11=0.f;
#pragma unroll
            for (int q=0;q<6;q++){
                const float4 a4 = *(const float4*)(&sH [4*q]);
                const float4 b4 = *(const float4*)(&sH [SP+4*q]);
                const float4 c4 = *(const float4*)(&sHP[4*q]);
                const float4 d4 = *(const float4*)(&sHP[SP+4*q]);
                S00 += c4.x*a4.x; S01 += c4.x*b4.x; S10 += d4.x*a4.x; S11 += d4.x*b4.x;
                if (4*q+1 < 21) { S00 += c4.y*a4.y; S01 += c4.y*b4.y; S10 += d4.y*a4.y; S11 += d4.y*b4.y; }
                if (4*q+2 < 21) { S00 += c4.z*a4.z; S01 += c4.z*b4.z; S10 += d4.z*a4.z; S11 += d4.z*b4.z; }
                if (4*q+3 < 21) { S00 += c4.w*a4.w; S01 += c4.w*b4.w; S10 += d4.w*a4.w; S11 += d4.w*b4.w; }
            }
            S00 += mcv0; S11 += mcv1;
            if (l < 21) {
                const float b0 = sHPT[l], b1 = sHPT[SP+l];
                float x0, x1;
                if (fabsf(S00) >= fabsf(S10)) {        // LU partial pivot (ties keep row 0)
                    const float fac = S10/S00;
                    x1 = (b1 - fac*b0) / (S11 - fac*S01);
                    x0 = (b0 - S01*x1) / S00;
                } else {
                    const float fac = S00/S10;
                    x1 = (b0 - fac*b1) / (S01 - fac*S11);
                    x0 = (b1 - S11*x1) / S10;
                }
                sK0[l] = x0; sK1[l] = x1;
                sKS0[l] = S00*x0 + S01*x1;             // (S @ K^T) rows, for K S K^T
                sKS1[l] = S10*x0 + S11*x1;
                sdx[l]  = x0*sr[0] + x1*sr[1];
            }
        }

        // ====== phase 5: Joseph update (both orientations) + state update =====
        __syncthreads();
        float dxr[21];
        if (repl) {
#pragma unroll
            for (int q=0;q<6;q++){
                const float4 x = *(const float4*)(&sdx[4*q]);
                dxr[4*q] = x.x;
                if (4*q+1 < 21) dxr[4*q+1] = x.y;
                if (4*q+2 < 21) dxr[4*q+2] = x.z;
                if (4*q+3 < 21) dxr[4*q+3] = x.w;
            }
        }
        if (act) {
            const float pn_ij = sPn[i_row*LDP + lj];
            const float pn_ji = sPn[lj*LDP + i_row];
            const float k0i  = sK0[i_row], k1i = sK1[i_row];
            const float k0j  = sK0[lj],    k1j = sK1[lj];
            const float hp0i = sHP[i_row], hp1i = sHP[SP+i_row];
            const float hp0j = sHP[lj],    hp1j = sHP[SP+lj];
            const float ht0i = sHPT[i_row], ht1i = sHPT[SP+i_row];
            const float ht0j = sHPT[lj],    ht1j = sHPT[SP+lj];
            const float ks0i = sKS0[i_row], ks1i = sKS1[i_row];
            const float ks0j = sKS0[lj],    ks1j = sKS1[lj];
            const float puij = pn_ij - (k0i*hp0j + k1i*hp1j) - (ht0i*k0j + ht1i*k1j)
                                     + (k0i*ks0j + k1i*ks1j);
            const float puji = pn_ji - (k0j*hp0i + k1j*hp1i) - (ht0j*k0i + ht1j*k1i)
                                     + (k0j*ks0i + k1j*ks1i);
            Preg = 0.5f*(puij + puji);
        }
        if (repl) {
            float dR[9], Jm[9];
            const float q0 = dxr[0], q1 = dxr[1], q2 = dxr[2];
            const float sq = q0*q0 + q1*q1 + q2*q2;
            if (sq < 1e-16f) {
                dR[0]=1.f; dR[1]=-q2; dR[2]=q1;
                dR[3]=q2;  dR[4]=1.f; dR[5]=-q0;
                dR[6]=-q1; dR[7]=q0;  dR[8]=1.f;
                Jm[0]=1.f;      Jm[1]=-0.5f*q2; Jm[2]=0.5f*q1;
                Jm[3]=0.5f*q2;  Jm[4]=1.f;      Jm[5]=-0.5f*q0;
                Jm[6]=-0.5f*q1; Jm[7]=0.5f*q0;  Jm[8]=1.f;
            } else {
                const float ang = sqrtf(sq);
                const float ax=q0/ang, ay=q1/ang, az=q2/ang;
                const float s=sinf(ang), c=cosf(ang), o=1.f-c;
                dR[0]=c+o*ax*ax;    dR[1]=o*ax*ay-s*az; dR[2]=o*ax*az+s*ay;
                dR[3]=o*ay*ax+s*az; dR[4]=c+o*ay*ay;    dR[5]=o*ay*az-s*ax;
                dR[6]=o*az*ax-s*ay; dR[7]=o*az*ay+s*ax; dR[8]=c+o*az*az;
                const float sa  = s/ang;
                const float osa = 1.f - sa;
                const float tt  = o/ang;
                Jm[0]=sa+osa*ax*ax;    Jm[1]=osa*ax*ay-tt*az; Jm[2]=osa*ax*az+tt*ay;
                Jm[3]=osa*ay*ax+tt*az; Jm[4]=sa+osa*ay*ay;    Jm[5]=osa*ay*az-tt*ax;
                Jm[6]=osa*az*ax-tt*ay; Jm[7]=osa*az*ay+tt*ax; Jm[8]=sa+osa*az*az;
            }
            float nR[9]; m3mul_dev(dR, Rot_n, nR);
#pragma unroll
            for (int c=0;c<9;c++) Rot[c] = nR[c];
            const float dv0 = Jm[0]*dxr[3] + Jm[1]*dxr[4] + Jm[2]*dxr[5];
            const float dv1 = Jm[3]*dxr[3] + Jm[4]*dxr[4] + Jm[5]*dxr[5];
            const float dv2 = Jm[6]*dxr[3] + Jm[7]*dxr[4] + Jm[8]*dxr[5];
            const float dp0 = Jm[0]*dxr[6] + Jm[1]*dxr[7] + Jm[2]*dxr[8];
            const float dp1 = Jm[3]*dxr[6] + Jm[4]*dxr[7] + Jm[5]*dxr[8];
            const float dp2 = Jm[6]*dxr[6] + Jm[7]*dxr[7] + Jm[8]*dxr[8];
            const float nv0 = dR[0]*v_n[0] + dR[1]*v_n[1] + dR[2]*v_n[2] + dv0;
            const float nv1 = dR[3]*v_n[0] + dR[4]*v_n[1] + dR[5]*v_n[2] + dv1;
            const float nv2 = dR[6]*v_n[0] + dR[7]*v_n[1] + dR[8]*v_n[2] + dv2;
            const float np0 = dR[0]*p_n[0] + dR[1]*p_n[1] + dR[2]*p_n[2] + dp0;
            const float np1 = dR[3]*p_n[0] + dR[4]*p_n[1] + dR[5]*p_n[2] + dp1;
            const float np2v = dR[6]*p_n[0] + dR[7]*p_n[1] + dR[8]*p_n[2] + dp2;
            vv[0]=nv0; vv[1]=nv1; vv[2]=nv2;
            pp[0]=np0; pp[1]=np1; pp[2]=np2v;
            bw[0]+=dxr[9];  bw[1]+=dxr[10]; bw[2]+=dxr[11];
            ba[0]+=dxr[12]; ba[1]+=dxr[13]; ba[2]+=dxr[14];
            float E2[9]; so3exp_dev(dxr[15], dxr[16], dxr[17], E2);
            float nRc[9]; m3mul_dev(E2, Rci, nRc);
#pragma unroll
            for (int c=0;c<9;c++) Rci[c] = nRc[c];
            tci[0]+=dxr[18]; tci[1]+=dxr[19]; tci[2]+=dxr[20];
        }
        STORE_TRAJ(n+1);

        // ---- rotate software pipeline ----
        t_cur = tn_c;
        tn_c  = tn_n;
        uc0=un0; uc1=un1; uc2=un2; uc3=un3; uc4=un4; uc5=un5;
        mcc0=mcn0; mcc1=mcn1;
        // no trailing barrier needed: next phase-0 writes touch only sA/sH/sr.
        // sA's last reader is phase 1 (4 barriers upstream); sH/sr's last
        // reader is phase 4, separated from the next write by the phase-5
        // barrier. One barrier suffices for write-after-read ordering.
    }
}

extern "C" void kernel_launch(void* const* d_in, const int* in_sizes, int n_in,
                              void* d_out, int out_size, void* d_ws, size_t ws_size,
                              hipStream_t stream) {
    const float* t     = (const float*)d_in[0];
    const float* u     = (const float*)d_in[1];
    const float* mc    = (const float*)d_in[2];
    const float* v_mes = (const float*)d_in[3];
    const float* ang0  = (const float*)d_in[5];
    float* out = (float*)d_out;
    const int N = in_sizes[0];
    (void)d_ws; (void)ws_size; (void)n_in; (void)out_size;
    iekf_scan_kernel<<<1, 448, 0, stream>>>(t, u, mc, v_mes, ang0, out, N);
}